// Round 1
// baseline (1757.839 us; speedup 1.0000x reference)
//
#include <hip/hip_runtime.h>
#include <stdint.h>

typedef __bf16 bf16x8 __attribute__((ext_vector_type(8)));
typedef float f32x4 __attribute__((ext_vector_type(4)));
typedef unsigned short us4 __attribute__((ext_vector_type(4)));

#define DIMC 384
#define HEADS 8
#define BATCH 4
#define HW 16384
#define C3 1152
#define CHD 48

__device__ __forceinline__ unsigned short f2b(float f) {
  unsigned int u = __float_as_uint(f);
  u = (u + 0x7fffu + ((u >> 16) & 1u)) >> 16;
  return (unsigned short)u;
}
__device__ __forceinline__ float b2f(unsigned short h) {
  return __uint_as_float(((unsigned int)h) << 16);
}

// ---------------- spectral sigma: scale = 1/(|Wm unit(Wm^T u)| + eps) --------
__global__ __launch_bounds__(256) void k_sigma(
    const float* __restrict__ qkv_w, const float* __restrict__ dw_w,
    const float* __restrict__ proj_w, const float* __restrict__ u_qkv,
    const float* __restrict__ u_dw, const float* __restrict__ u_proj,
    float* __restrict__ scales) {
  const float* W; const float* u; int H, Kc;
  if (blockIdx.x == 0) { W = qkv_w; u = u_qkv; H = C3; Kc = DIMC; }
  else if (blockIdx.x == 1) { W = dw_w; u = u_dw; H = C3; Kc = 9; }
  else { W = proj_w; u = u_proj; H = DIMC; Kc = DIMC; }
  __shared__ float v[DIMC];
  __shared__ float red[256];
  int tid = threadIdx.x;
  // t = W^T u
  for (int c = tid; c < Kc; c += 256) {
    float s = 0.f;
    for (int r = 0; r < H; ++r) s += W[(long)r * Kc + c] * u[r];
    v[c] = s;
  }
  __syncthreads();
  float ss = 0.f;
  for (int c = tid; c < Kc; c += 256) ss += v[c] * v[c];
  red[tid] = ss; __syncthreads();
  for (int s = 128; s > 0; s >>= 1) { if (tid < s) red[tid] += red[tid + s]; __syncthreads(); }
  float inv = 1.0f / fmaxf(sqrtf(red[0]), 1e-12f);
  __syncthreads();
  for (int c = tid; c < Kc; c += 256) v[c] *= inv;
  __syncthreads();
  // s = W v ; sigma = |s|
  float ss2 = 0.f;
  for (int r = tid; r < H; r += 256) {
    float s = 0.f;
    for (int c = 0; c < Kc; ++c) s += W[(long)r * Kc + c] * v[c];
    ss2 += s * s;
  }
  red[tid] = ss2; __syncthreads();
  for (int s = 128; s > 0; s >>= 1) { if (tid < s) red[tid] += red[tid + s]; __syncthreads(); }
  if (tid == 0) scales[blockIdx.x] = 1.0f / (sqrtf(red[0]) + 1e-12f);
}

// ---------------- scale + convert weights -----------------------------------
__global__ __launch_bounds__(256) void k_prep(
    const float* __restrict__ qkv_w, const float* __restrict__ dw_w,
    const float* __restrict__ proj_w, const float* __restrict__ scales,
    unsigned short* __restrict__ wq, unsigned short* __restrict__ wp,
    float* __restrict__ wd) {
  int i = blockIdx.x * 256 + threadIdx.x;
  float sq = scales[0], sd = scales[1], sp = scales[2];
  if (i < C3 * DIMC) wq[i] = f2b(qkv_w[i] * sq);
  if (i < DIMC * DIMC) wp[i] = f2b(proj_w[i] * sp);
  if (i < C3 * 9) wd[i] = dw_w[i] * sd;
}

// ---------------- x (B,C,HW) fp32 -> xT (B,HW,C) bf16 ------------------------
__global__ __launch_bounds__(256) void k_transpose(
    const float* __restrict__ x, unsigned short* __restrict__ xT) {
  __shared__ float tile[32][33];
  int b = blockIdx.z;
  int c0 = blockIdx.y * 32, n0 = blockIdx.x * 32;
  int tx = threadIdx.x & 31, ty = threadIdx.x >> 5;
  const float* xb = x + (long)b * DIMC * HW;
  for (int i = ty; i < 32; i += 8)
    tile[i][tx] = xb[(long)(c0 + i) * HW + n0 + tx];
  __syncthreads();
  unsigned short* xTb = xT + (long)b * HW * DIMC;
  for (int i = ty; i < 32; i += 8)
    xTb[(long)(n0 + i) * DIMC + c0 + tx] = f2b(tile[tx][i]);
}

// ---------------- bf16 MFMA GEMM, C = A(MxK) * BT(NxK)^T ---------------------
template <bool BF16_OUT>
__global__ __launch_bounds__(256) void gemm_bt(
    const unsigned short* __restrict__ A, const unsigned short* __restrict__ BT,
    void* __restrict__ Cv, int M, int N, int K, long sB, long sC) {
  __shared__ __align__(16) unsigned short As[128][32];
  __shared__ __align__(16) unsigned short Bs[128][32];
  const unsigned short* Ab = A;  // weights shared across batch
  const unsigned short* Bb = BT + (long)blockIdx.z * sB;
  int tid = threadIdx.x;
  int m0 = blockIdx.y * 128, n0 = blockIdx.x * 128;
  int wave = tid >> 6, lane = tid & 63;
  int wm = (wave >> 1) * 64, wn = (wave & 1) * 64;
  int qm = lane & 15, qko = (lane >> 4) * 8;
  int r0 = tid >> 2, ko0 = (tid & 3) * 8;
  f32x4 acc[4][4] = {};
  for (int k0 = 0; k0 < K; k0 += 32) {
    __syncthreads();
    *(int4*)(&As[r0][ko0]) = *(const int4*)(Ab + (long)(m0 + r0) * K + k0 + ko0);
    *(int4*)(&As[r0 + 64][ko0]) = *(const int4*)(Ab + (long)(m0 + r0 + 64) * K + k0 + ko0);
    *(int4*)(&Bs[r0][ko0]) = *(const int4*)(Bb + (long)(n0 + r0) * K + k0 + ko0);
    *(int4*)(&Bs[r0 + 64][ko0]) = *(const int4*)(Bb + (long)(n0 + r0 + 64) * K + k0 + ko0);
    __syncthreads();
    bf16x8 av[4], bv[4];
#pragma unroll
    for (int i = 0; i < 4; ++i) av[i] = *(const bf16x8*)(&As[wm + i * 16 + qm][qko]);
#pragma unroll
    for (int i = 0; i < 4; ++i) bv[i] = *(const bf16x8*)(&Bs[wn + i * 16 + qm][qko]);
#pragma unroll
    for (int mi = 0; mi < 4; ++mi)
#pragma unroll
      for (int ni = 0; ni < 4; ++ni)
        acc[mi][ni] = __builtin_amdgcn_mfma_f32_16x16x32_bf16(av[mi], bv[ni], acc[mi][ni], 0, 0, 0);
  }
  int col = lane & 15, rowq = (lane >> 4) * 4;
  if (BF16_OUT) {
    unsigned short* Cb = (unsigned short*)Cv + (long)blockIdx.z * sC;
    for (int mi = 0; mi < 4; ++mi)
      for (int ni = 0; ni < 4; ++ni)
        for (int r = 0; r < 4; ++r) {
          int m = m0 + wm + mi * 16 + rowq + r;
          int n = n0 + wn + ni * 16 + col;
          Cb[(long)m * N + n] = f2b(acc[mi][ni][r]);
        }
  } else {
    float* Cb = (float*)Cv + (long)blockIdx.z * sC;
    for (int mi = 0; mi < 4; ++mi)
      for (int ni = 0; ni < 4; ++ni)
        for (int r = 0; r < 4; ++r) {
          int m = m0 + wm + mi * 16 + rowq + r;
          int n = n0 + wn + ni * 16 + col;
          Cb[(long)m * N + n] = acc[mi][ni][r];
        }
  }
}

// ---------------- depthwise 3x3 (SAME) + sumsq for q/k channels --------------
__global__ __launch_bounds__(256) void k_dwconv(
    const unsigned short* __restrict__ qkv, const float* __restrict__ wd,
    unsigned short* __restrict__ out, float* __restrict__ sumsq) {
  int b = blockIdx.z, c = blockIdx.y, h0 = blockIdx.x * 32;
  const unsigned short* in = qkv + ((long)b * C3 + c) * HW;
  unsigned short* o = out + ((long)b * C3 + c) * HW;
  float w[9];
#pragma unroll
  for (int i = 0; i < 9; ++i) w[i] = wd[c * 9 + i];
  int tid = threadIdx.x;
  float ss = 0.f;
  for (int p = tid; p < 32 * 128; p += 256) {
    int y = h0 + (p >> 7), x = p & 127;
    float acc = 0.f;
#pragma unroll
    for (int dy = -1; dy <= 1; ++dy) {
      int yy = y + dy;
      if (yy < 0 || yy > 127) continue;
#pragma unroll
      for (int dx = -1; dx <= 1; ++dx) {
        int xx = x + dx;
        if (xx < 0 || xx > 127) continue;
        acc += b2f(in[yy * 128 + xx]) * w[(dy + 1) * 3 + (dx + 1)];
      }
    }
    unsigned short ob = f2b(acc);
    o[y * 128 + x] = ob;
    float av = b2f(ob);
    ss += av * av;
  }
  __shared__ float red[256];
  red[tid] = ss; __syncthreads();
  for (int s = 128; s > 0; s >>= 1) { if (tid < s) red[tid] += red[tid + s]; __syncthreads(); }
  if (tid == 0 && c < 2 * DIMC) atomicAdd(&sumsq[b * 2 * DIMC + c], red[0]);
}

// ---------------- S = Q K^T (unnormalized), fp32 atomic partials -------------
__global__ __launch_bounds__(64) void k_qk(
    const unsigned short* __restrict__ dwo, float* __restrict__ S) {
  int bh = blockIdx.z, b = bh >> 3, h = bh & 7;
  int tile = blockIdx.y;
  int tm = (tile / 3) * 16, tn = (tile % 3) * 16;
  int k0 = blockIdx.x * 2048;
  const unsigned short* Q = dwo + ((long)b * C3 + h * CHD) * HW;
  const unsigned short* Km = dwo + ((long)b * C3 + DIMC + h * CHD) * HW;
  int lane = threadIdx.x;
  int fm = lane & 15, fk = (lane >> 4) * 8;
  const unsigned short* qrow = Q + (long)(tm + fm) * HW;
  const unsigned short* krow = Km + (long)(tn + fm) * HW;
  f32x4 acc = {};
  for (int k = k0; k < k0 + 2048; k += 32) {
    bf16x8 a = *(const bf16x8*)(qrow + k + fk);
    bf16x8 bv = *(const bf16x8*)(krow + k + fk);
    acc = __builtin_amdgcn_mfma_f32_16x16x32_bf16(a, bv, acc, 0, 0, 0);
  }
  int col = lane & 15, rowq = (lane >> 4) * 4;
  float* Sb = S + (long)bh * CHD * CHD;
#pragma unroll
  for (int r = 0; r < 4; ++r)
    atomicAdd(&Sb[(tm + rowq + r) * CHD + tn + col], acc[r]);
}

// ---------------- normalize + temperature + clamp + softmax -> P bf16 (48x64) -
__global__ __launch_bounds__(64) void k_softmax(
    const float* __restrict__ S, const float* __restrict__ sumsq,
    const float* __restrict__ temperature, unsigned short* __restrict__ P) {
  int bh = blockIdx.x, b = bh >> 3, h = bh & 7;
  float t = temperature[h];
  const float* Sb = S + (long)bh * CHD * CHD;
  const float* nq = sumsq + b * 2 * DIMC + h * CHD;
  const float* nk = sumsq + b * 2 * DIMC + DIMC + h * CHD;
  unsigned short* Pb = P + (long)bh * CHD * 64;
  int i = threadIdx.x;
  if (i < CHD) {
    float qn = fmaxf(sqrtf(nq[i]), 1e-12f);
    float row[CHD];
    float mx = -1e30f;
#pragma unroll
    for (int j = 0; j < CHD; ++j) {
      float kn = fmaxf(sqrtf(nk[j]), 1e-12f);
      float v = Sb[i * CHD + j] / (qn * kn) * t;
      v = fminf(fmaxf(v, -50.f), 50.f);
      row[j] = v;
      mx = fmaxf(mx, v);
    }
    float sum = 0.f;
#pragma unroll
    for (int j = 0; j < CHD; ++j) { float e = __expf(row[j] - mx); row[j] = e; sum += e; }
    float inv = 1.0f / sum;
#pragma unroll
    for (int j = 0; j < 64; ++j)
      Pb[i * 64 + j] = f2b(j < CHD ? row[j] * inv : 0.0f);
  }
}

// ---------------- O^T = (P @ V)^T, bf16, (B, HW, 384) ------------------------
__global__ __launch_bounds__(256) void k_pv(
    const unsigned short* __restrict__ P, const unsigned short* __restrict__ dwo,
    unsigned short* __restrict__ OT) {
  int bh = blockIdx.z, b = bh >> 3, h = bh & 7;
  int tm = blockIdx.y * 16;
  int wave = threadIdx.x >> 6, lane = threadIdx.x & 63;
  int fm = lane & 15, fq = lane >> 4;
  const unsigned short* Pb = P + (long)bh * CHD * 64;
  const unsigned short* V = dwo + ((long)b * C3 + 2 * DIMC + h * CHD) * HW;
  bf16x8 a0 = *(const bf16x8*)(Pb + (tm + fm) * 64 + fq * 8);
  bf16x8 a1 = *(const bf16x8*)(Pb + (tm + fm) * 64 + 32 + fq * 8);
  unsigned short* OTb = OT + (long)b * HW * DIMC;
  for (int nt = 0; nt < 4; ++nt) {
    int n0 = (blockIdx.x * 16 + wave * 4 + nt) * 16;
    bf16x8 b0, b1;
#pragma unroll
    for (int j = 0; j < 8; ++j) {
      int kk0 = fq * 8 + j;
      ((__bf16*)&b0)[j] = *(const __bf16*)(V + (long)kk0 * HW + n0 + fm);
      int kk1 = 32 + fq * 8 + j;
      ((__bf16*)&b1)[j] = (kk1 < CHD) ? *(const __bf16*)(V + (long)kk1 * HW + n0 + fm)
                                      : (__bf16)0.0f;
    }
    f32x4 acc = {};
    acc = __builtin_amdgcn_mfma_f32_16x16x32_bf16(a0, b0, acc, 0, 0, 0);
    acc = __builtin_amdgcn_mfma_f32_16x16x32_bf16(a1, b1, acc, 0, 0, 0);
    int n = n0 + (lane & 15);
    int cg = h * CHD + tm + fq * 4;
    us4 st;
#pragma unroll
    for (int r = 0; r < 4; ++r) st[r] = f2b(acc[r]);
    *(us4*)(OTb + (long)n * DIMC + cg) = st;
  }
}

extern "C" void kernel_launch(void* const* d_in, const int* in_sizes, int n_in,
                              void* d_out, int out_size, void* d_ws, size_t ws_size,
                              hipStream_t stream) {
  const float* x = (const float*)d_in[0];
  const float* qkv_w = (const float*)d_in[1];
  const float* dw_w = (const float*)d_in[2];
  const float* proj_w = (const float*)d_in[3];
  const float* temp = (const float*)d_in[4];
  const float* u_qkv = (const float*)d_in[5];
  const float* u_dw = (const float*)d_in[6];
  const float* u_proj = (const float*)d_in[7];
  float* out = (float*)d_out;

  char* ws = (char*)d_ws;
  size_t cur = 0;
  auto take = [&](size_t n) { size_t r = cur; cur += (n + 255) & ~(size_t)255; return r; };
  float* scales = (float*)(ws + take(3 * 4));
  float* sumsq = (float*)(ws + take((size_t)BATCH * 2 * DIMC * 4));
  float* S = (float*)(ws + take((size_t)32 * CHD * CHD * 4));
  unsigned short* P = (unsigned short*)(ws + take((size_t)32 * CHD * 64 * 2));
  unsigned short* wq = (unsigned short*)(ws + take((size_t)C3 * DIMC * 2));
  unsigned short* wp = (unsigned short*)(ws + take((size_t)DIMC * DIMC * 2));
  float* wd = (float*)(ws + take((size_t)C3 * 9 * 4));
  unsigned short* xT = (unsigned short*)(ws + take((size_t)BATCH * HW * DIMC * 2));
  unsigned short* qkv = (unsigned short*)(ws + take((size_t)BATCH * C3 * HW * 2));
  unsigned short* dwo = (unsigned short*)(ws + take((size_t)BATCH * C3 * HW * 2));
  unsigned short* OT = xT;  // xT is dead after gemm1; reuse for O^T

  hipMemsetAsync(sumsq, 0, (size_t)BATCH * 2 * DIMC * 4, stream);
  hipMemsetAsync(S, 0, (size_t)32 * CHD * CHD * 4, stream);

  k_sigma<<<dim3(3), dim3(256), 0, stream>>>(qkv_w, dw_w, proj_w, u_qkv, u_dw, u_proj, scales);
  k_prep<<<dim3((C3 * DIMC + 255) / 256), dim3(256), 0, stream>>>(qkv_w, dw_w, proj_w, scales, wq, wp, wd);
  k_transpose<<<dim3(HW / 32, DIMC / 32, BATCH), dim3(256), 0, stream>>>(x, xT);
  gemm_bt<true><<<dim3(HW / 128, C3 / 128, BATCH), dim3(256), 0, stream>>>(
      wq, xT, qkv, C3, HW, DIMC, (long)HW * DIMC, (long)C3 * HW);
  k_dwconv<<<dim3(4, C3, BATCH), dim3(256), 0, stream>>>(qkv, wd, dwo, sumsq);
  k_qk<<<dim3(8, 9, 32), dim3(64), 0, stream>>>(dwo, S);
  k_softmax<<<dim3(32), dim3(64), 0, stream>>>(S, sumsq, temp, P);
  k_pv<<<dim3(64, 3, 32), dim3(256), 0, stream>>>(P, dwo, OT);
  gemm_bt<false><<<dim3(HW / 128, DIMC / 128, BATCH), dim3(256), 0, stream>>>(
      wp, OT, out, DIMC, HW, DIMC, (long)HW * DIMC, (long)DIMC * HW);
}

// Round 2
// 924.383 us; speedup vs baseline: 1.9016x; 1.9016x over previous
//
#include <hip/hip_runtime.h>
#include <stdint.h>

typedef __bf16 bf16x8 __attribute__((ext_vector_type(8)));
typedef float f32x4 __attribute__((ext_vector_type(4)));
typedef unsigned short us4 __attribute__((ext_vector_type(4)));

#define DIMC 384
#define HEADS 8
#define BATCH 4
#define HW 16384
#define C3 1152
#define CHD 48

__device__ __forceinline__ unsigned short f2b(float f) {
  unsigned int u = __float_as_uint(f);
  u = (u + 0x7fffu + ((u >> 16) & 1u)) >> 16;
  return (unsigned short)u;
}
__device__ __forceinline__ float b2f(unsigned short h) {
  return __uint_as_float(((unsigned int)h) << 16);
}

// ---------------- power iteration stage 1: t = W^T u (qkv, proj) -------------
__global__ __launch_bounds__(384) void k_wtu(
    const float* __restrict__ qkv_w, const float* __restrict__ proj_w,
    const float* __restrict__ u_qkv, const float* __restrict__ u_proj,
    float* __restrict__ t0, float* __restrict__ t2) {
  int mat = blockIdx.y;
  const float* W = mat ? proj_w : qkv_w;
  const float* u = mat ? u_proj : u_qkv;
  float* t = mat ? t2 : t0;
  int H = mat ? DIMC : C3;
  int r0 = blockIdx.x * 128;
  if (r0 >= H) return;
  int c = threadIdx.x;  // < 384, coalesced over columns
  float acc = 0.f;
  int rend = min(r0 + 128, H);
  for (int r = r0; r < rend; ++r) acc += W[(long)r * DIMC + c] * u[r];
  atomicAdd(&t[c], acc);
}

// ---------------- stage 1 for depthwise weight (1152x9) ----------------------
__global__ __launch_bounds__(256) void k_wtu_dw(
    const float* __restrict__ dw_w, const float* __restrict__ u_dw,
    float* __restrict__ t1) {
  float acc[9] = {};
  for (int r = threadIdx.x; r < C3; r += 256) {
    float ur = u_dw[r];
#pragma unroll
    for (int j = 0; j < 9; ++j) acc[j] += dw_w[r * 9 + j] * ur;
  }
  __shared__ float sh[9];
  if (threadIdx.x < 9) sh[threadIdx.x] = 0.f;
  __syncthreads();
#pragma unroll
  for (int j = 0; j < 9; ++j) atomicAdd(&sh[j], acc[j]);
  __syncthreads();
  if (threadIdx.x < 9) t1[threadIdx.x] = sh[threadIdx.x];
}

// ---------------- stage 2: sig2[mat] = |W t|^2, one wave per row -------------
__global__ __launch_bounds__(256) void k_wv(
    const float* __restrict__ qkv_w, const float* __restrict__ dw_w,
    const float* __restrict__ proj_w, const float* __restrict__ t0,
    const float* __restrict__ t1, const float* __restrict__ t2,
    float* __restrict__ sig2) {
  int mat = blockIdx.y;
  const float* W; const float* t; int H, Kc;
  if (mat == 0) { W = qkv_w; t = t0; H = C3; Kc = DIMC; }
  else if (mat == 1) { W = dw_w; t = t1; H = C3; Kc = 9; }
  else { W = proj_w; t = t2; H = DIMC; Kc = DIMC; }
  int wave = threadIdx.x >> 6, lane = threadIdx.x & 63;
  int r = blockIdx.x * 4 + wave;
  if (r >= H) return;
  float acc = 0.f;
  for (int c = lane; c < Kc; c += 64) acc += W[(long)r * Kc + c] * t[c];
  for (int off = 32; off; off >>= 1) acc += __shfl_down(acc, off);
  if (lane == 0) atomicAdd(&sig2[mat], acc * acc);
}

// ---------------- stage 3: scales[mat] = 1/(sqrt(sig2)/max(|t|,eps) + eps) ---
__global__ __launch_bounds__(256) void k_scale(
    const float* __restrict__ t0, const float* __restrict__ t1,
    const float* __restrict__ t2, const float* __restrict__ sig2,
    float* __restrict__ scales) {
  __shared__ float red[256];
  int tid = threadIdx.x;
  const float* ts[3] = {t0, t1, t2};
  const int ks[3] = {DIMC, 9, DIMC};
  for (int m = 0; m < 3; ++m) {
    float ss = 0.f;
    for (int c = tid; c < ks[m]; c += 256) ss += ts[m][c] * ts[m][c];
    red[tid] = ss; __syncthreads();
    for (int s = 128; s; s >>= 1) { if (tid < s) red[tid] += red[tid + s]; __syncthreads(); }
    if (tid == 0) {
      float tn = fmaxf(sqrtf(red[0]), 1e-12f);
      float sigma = sqrtf(sig2[m]) / tn;
      scales[m] = 1.0f / (sigma + 1e-12f);
    }
    __syncthreads();
  }
}

// ---------------- scale + convert weights -----------------------------------
__global__ __launch_bounds__(256) void k_prep(
    const float* __restrict__ qkv_w, const float* __restrict__ dw_w,
    const float* __restrict__ proj_w, const float* __restrict__ scales,
    unsigned short* __restrict__ wq, unsigned short* __restrict__ wp,
    float* __restrict__ wd) {
  int i = blockIdx.x * 256 + threadIdx.x;
  float sq = scales[0], sd = scales[1], sp = scales[2];
  if (i < C3 * DIMC) wq[i] = f2b(qkv_w[i] * sq);
  if (i < DIMC * DIMC) wp[i] = f2b(proj_w[i] * sp);
  if (i < C3 * 9) wd[i] = dw_w[i] * sd;
}

// ---------------- x (B,C,HW) fp32 -> xT (B,HW,C) bf16 ------------------------
__global__ __launch_bounds__(256) void k_transpose(
    const float* __restrict__ x, unsigned short* __restrict__ xT) {
  __shared__ float tile[32][33];
  int b = blockIdx.z;
  int c0 = blockIdx.y * 32, n0 = blockIdx.x * 32;
  int tx = threadIdx.x & 31, ty = threadIdx.x >> 5;
  const float* xb = x + (long)b * DIMC * HW;
  for (int i = ty; i < 32; i += 8)
    tile[i][tx] = xb[(long)(c0 + i) * HW + n0 + tx];
  __syncthreads();
  unsigned short* xTb = xT + (long)b * HW * DIMC;
  for (int i = ty; i < 32; i += 8)
    xTb[(long)(n0 + i) * DIMC + c0 + tx] = f2b(tile[tx][i]);
}

// ---------------- bf16 MFMA GEMM, C = A(MxK) * BT(NxK)^T ---------------------
template <bool BF16_OUT>
__global__ __launch_bounds__(256) void gemm_bt(
    const unsigned short* __restrict__ A, const unsigned short* __restrict__ BT,
    void* __restrict__ Cv, int M, int N, int K, long sB, long sC) {
  __shared__ __align__(16) unsigned short As[128][32];
  __shared__ __align__(16) unsigned short Bs[128][32];
  const unsigned short* Ab = A;  // weights shared across batch
  const unsigned short* Bb = BT + (long)blockIdx.z * sB;
  int tid = threadIdx.x;
  int m0 = blockIdx.y * 128, n0 = blockIdx.x * 128;
  int wave = tid >> 6, lane = tid & 63;
  int wm = (wave >> 1) * 64, wn = (wave & 1) * 64;
  int qm = lane & 15, qko = (lane >> 4) * 8;
  int r0 = tid >> 2, ko0 = (tid & 3) * 8;
  f32x4 acc[4][4] = {};
  for (int k0 = 0; k0 < K; k0 += 32) {
    __syncthreads();
    *(int4*)(&As[r0][ko0]) = *(const int4*)(Ab + (long)(m0 + r0) * K + k0 + ko0);
    *(int4*)(&As[r0 + 64][ko0]) = *(const int4*)(Ab + (long)(m0 + r0 + 64) * K + k0 + ko0);
    *(int4*)(&Bs[r0][ko0]) = *(const int4*)(Bb + (long)(n0 + r0) * K + k0 + ko0);
    *(int4*)(&Bs[r0 + 64][ko0]) = *(const int4*)(Bb + (long)(n0 + r0 + 64) * K + k0 + ko0);
    __syncthreads();
    bf16x8 av[4], bv[4];
#pragma unroll
    for (int i = 0; i < 4; ++i) av[i] = *(const bf16x8*)(&As[wm + i * 16 + qm][qko]);
#pragma unroll
    for (int i = 0; i < 4; ++i) bv[i] = *(const bf16x8*)(&Bs[wn + i * 16 + qm][qko]);
#pragma unroll
    for (int mi = 0; mi < 4; ++mi)
#pragma unroll
      for (int ni = 0; ni < 4; ++ni)
        acc[mi][ni] = __builtin_amdgcn_mfma_f32_16x16x32_bf16(av[mi], bv[ni], acc[mi][ni], 0, 0, 0);
  }
  int col = lane & 15, rowq = (lane >> 4) * 4;
  if (BF16_OUT) {
    unsigned short* Cb = (unsigned short*)Cv + (long)blockIdx.z * sC;
    for (int mi = 0; mi < 4; ++mi)
      for (int ni = 0; ni < 4; ++ni)
        for (int r = 0; r < 4; ++r) {
          int m = m0 + wm + mi * 16 + rowq + r;
          int n = n0 + wn + ni * 16 + col;
          Cb[(long)m * N + n] = f2b(acc[mi][ni][r]);
        }
  } else {
    float* Cb = (float*)Cv + (long)blockIdx.z * sC;
    for (int mi = 0; mi < 4; ++mi)
      for (int ni = 0; ni < 4; ++ni)
        for (int r = 0; r < 4; ++r) {
          int m = m0 + wm + mi * 16 + rowq + r;
          int n = n0 + wn + ni * 16 + col;
          Cb[(long)m * N + n] = acc[mi][ni][r];
        }
  }
}

// ---------------- depthwise 3x3 (SAME) + sumsq for q/k channels --------------
__global__ __launch_bounds__(256) void k_dwconv(
    const unsigned short* __restrict__ qkv, const float* __restrict__ wd,
    unsigned short* __restrict__ out, float* __restrict__ sumsq) {
  int b = blockIdx.z, c = blockIdx.y, h0 = blockIdx.x * 32;
  const unsigned short* in = qkv + ((long)b * C3 + c) * HW;
  unsigned short* o = out + ((long)b * C3 + c) * HW;
  float w[9];
#pragma unroll
  for (int i = 0; i < 9; ++i) w[i] = wd[c * 9 + i];
  int tid = threadIdx.x;
  float ss = 0.f;
  for (int p = tid; p < 32 * 128; p += 256) {
    int y = h0 + (p >> 7), x = p & 127;
    float acc = 0.f;
#pragma unroll
    for (int dy = -1; dy <= 1; ++dy) {
      int yy = y + dy;
      if (yy < 0 || yy > 127) continue;
#pragma unroll
      for (int dx = -1; dx <= 1; ++dx) {
        int xx = x + dx;
        if (xx < 0 || xx > 127) continue;
        acc += b2f(in[yy * 128 + xx]) * w[(dy + 1) * 3 + (dx + 1)];
      }
    }
    unsigned short ob = f2b(acc);
    o[y * 128 + x] = ob;
    float av = b2f(ob);
    ss += av * av;
  }
  __shared__ float red[256];
  red[tid] = ss; __syncthreads();
  for (int s = 128; s > 0; s >>= 1) { if (tid < s) red[tid] += red[tid + s]; __syncthreads(); }
  if (tid == 0 && c < 2 * DIMC) atomicAdd(&sumsq[b * 2 * DIMC + c], red[0]);
}

// ---------------- S = Q K^T (unnormalized), fp32 atomic partials -------------
__global__ __launch_bounds__(64) void k_qk(
    const unsigned short* __restrict__ dwo, float* __restrict__ S) {
  int bh = blockIdx.z, b = bh >> 3, h = bh & 7;
  int tile = blockIdx.y;
  int tm = (tile / 3) * 16, tn = (tile % 3) * 16;
  int k0 = blockIdx.x * 2048;
  const unsigned short* Q = dwo + ((long)b * C3 + h * CHD) * HW;
  const unsigned short* Km = dwo + ((long)b * C3 + DIMC + h * CHD) * HW;
  int lane = threadIdx.x;
  int fm = lane & 15, fk = (lane >> 4) * 8;
  const unsigned short* qrow = Q + (long)(tm + fm) * HW;
  const unsigned short* krow = Km + (long)(tn + fm) * HW;
  f32x4 acc = {};
  for (int k = k0; k < k0 + 2048; k += 32) {
    bf16x8 a = *(const bf16x8*)(qrow + k + fk);
    bf16x8 bv = *(const bf16x8*)(krow + k + fk);
    acc = __builtin_amdgcn_mfma_f32_16x16x32_bf16(a, bv, acc, 0, 0, 0);
  }
  int col = lane & 15, rowq = (lane >> 4) * 4;
  float* Sb = S + (long)bh * CHD * CHD;
#pragma unroll
  for (int r = 0; r < 4; ++r)
    atomicAdd(&Sb[(tm + rowq + r) * CHD + tn + col], acc[r]);
}

// ---------------- normalize + temperature + clamp + softmax -> P bf16 (48x64) -
__global__ __launch_bounds__(64) void k_softmax(
    const float* __restrict__ S, const float* __restrict__ sumsq,
    const float* __restrict__ temperature, unsigned short* __restrict__ P) {
  int bh = blockIdx.x, b = bh >> 3, h = bh & 7;
  float t = temperature[h];
  const float* Sb = S + (long)bh * CHD * CHD;
  const float* nq = sumsq + b * 2 * DIMC + h * CHD;
  const float* nk = sumsq + b * 2 * DIMC + DIMC + h * CHD;
  unsigned short* Pb = P + (long)bh * CHD * 64;
  int i = threadIdx.x;
  if (i < CHD) {
    float qn = fmaxf(sqrtf(nq[i]), 1e-12f);
    float row[CHD];
    float mx = -1e30f;
#pragma unroll
    for (int j = 0; j < CHD; ++j) {
      float kn = fmaxf(sqrtf(nk[j]), 1e-12f);
      float v = Sb[i * CHD + j] / (qn * kn) * t;
      v = fminf(fmaxf(v, -50.f), 50.f);
      row[j] = v;
      mx = fmaxf(mx, v);
    }
    float sum = 0.f;
#pragma unroll
    for (int j = 0; j < CHD; ++j) { float e = __expf(row[j] - mx); row[j] = e; sum += e; }
    float inv = 1.0f / sum;
#pragma unroll
    for (int j = 0; j < 64; ++j)
      Pb[i * 64 + j] = f2b(j < CHD ? row[j] * inv : 0.0f);
  }
}

// ---------------- O^T = (P @ V)^T, bf16, (B, HW, 384) ------------------------
__global__ __launch_bounds__(256) void k_pv(
    const unsigned short* __restrict__ P, const unsigned short* __restrict__ dwo,
    unsigned short* __restrict__ OT) {
  int bh = blockIdx.z, b = bh >> 3, h = bh & 7;
  int tm = blockIdx.y * 16;
  int wave = threadIdx.x >> 6, lane = threadIdx.x & 63;
  int fm = lane & 15, fq = lane >> 4;
  const unsigned short* Pb = P + (long)bh * CHD * 64;
  const unsigned short* V = dwo + ((long)b * C3 + 2 * DIMC + h * CHD) * HW;
  bf16x8 a0 = *(const bf16x8*)(Pb + (tm + fm) * 64 + fq * 8);
  bf16x8 a1 = *(const bf16x8*)(Pb + (tm + fm) * 64 + 32 + fq * 8);
  unsigned short* OTb = OT + (long)b * HW * DIMC;
  for (int nt = 0; nt < 4; ++nt) {
    int n0 = (blockIdx.x * 16 + wave * 4 + nt) * 16;
    bf16x8 b0, b1;
#pragma unroll
    for (int j = 0; j < 8; ++j) {
      int kk0 = fq * 8 + j;
      ((__bf16*)&b0)[j] = *(const __bf16*)(V + (long)kk0 * HW + n0 + fm);
      int kk1 = 32 + fq * 8 + j;
      ((__bf16*)&b1)[j] = (kk1 < CHD) ? *(const __bf16*)(V + (long)kk1 * HW + n0 + fm)
                                      : (__bf16)0.0f;
    }
    f32x4 acc = {};
    acc = __builtin_amdgcn_mfma_f32_16x16x32_bf16(a0, b0, acc, 0, 0, 0);
    acc = __builtin_amdgcn_mfma_f32_16x16x32_bf16(a1, b1, acc, 0, 0, 0);
    int n = n0 + (lane & 15);
    int cg = h * CHD + tm + fq * 4;
    us4 st;
#pragma unroll
    for (int r = 0; r < 4; ++r) st[r] = f2b(acc[r]);
    *(us4*)(OTb + (long)n * DIMC + cg) = st;
  }
}

extern "C" void kernel_launch(void* const* d_in, const int* in_sizes, int n_in,
                              void* d_out, int out_size, void* d_ws, size_t ws_size,
                              hipStream_t stream) {
  const float* x = (const float*)d_in[0];
  const float* qkv_w = (const float*)d_in[1];
  const float* dw_w = (const float*)d_in[2];
  const float* proj_w = (const float*)d_in[3];
  const float* temp = (const float*)d_in[4];
  const float* u_qkv = (const float*)d_in[5];
  const float* u_dw = (const float*)d_in[6];
  const float* u_proj = (const float*)d_in[7];
  float* out = (float*)d_out;

  char* ws = (char*)d_ws;
  size_t cur = 0;
  auto take = [&](size_t n) { size_t r = cur; cur += (n + 255) & ~(size_t)255; return r; };
  // power-iteration scratch: t0 | t1 | t2 | sig2 contiguous -> one memset
  float* t0 = (float*)(ws + take(DIMC * 4));        // 384
  float* t1 = (float*)(ws + take(16 * 4));          // 9 (padded)
  float* t2 = (float*)(ws + take(DIMC * 4));        // 384
  float* sig2 = (float*)(ws + take(4 * 4));         // 3
  size_t tbytes = cur;                              // all of the above
  float* scales = (float*)(ws + take(3 * 4));
  float* sumsq = (float*)(ws + take((size_t)BATCH * 2 * DIMC * 4));
  float* S = (float*)(ws + take((size_t)32 * CHD * CHD * 4));
  unsigned short* P = (unsigned short*)(ws + take((size_t)32 * CHD * 64 * 2));
  unsigned short* wq = (unsigned short*)(ws + take((size_t)C3 * DIMC * 2));
  unsigned short* wp = (unsigned short*)(ws + take((size_t)DIMC * DIMC * 2));
  float* wd = (float*)(ws + take((size_t)C3 * 9 * 4));
  unsigned short* xT = (unsigned short*)(ws + take((size_t)BATCH * HW * DIMC * 2));
  unsigned short* qkv = (unsigned short*)(ws + take((size_t)BATCH * C3 * HW * 2));
  unsigned short* dwo = (unsigned short*)(ws + take((size_t)BATCH * C3 * HW * 2));
  unsigned short* OT = xT;  // xT is dead after gemm1; reuse for O^T

  hipMemsetAsync(ws, 0, tbytes, stream);  // t0,t1,t2,sig2
  hipMemsetAsync(sumsq, 0, (size_t)BATCH * 2 * DIMC * 4, stream);
  hipMemsetAsync(S, 0, (size_t)32 * CHD * CHD * 4, stream);

  k_wtu<<<dim3(9, 2), dim3(384), 0, stream>>>(qkv_w, proj_w, u_qkv, u_proj, t0, t2);
  k_wtu_dw<<<dim3(1), dim3(256), 0, stream>>>(dw_w, u_dw, t1);
  k_wv<<<dim3(288, 3), dim3(256), 0, stream>>>(qkv_w, dw_w, proj_w, t0, t1, t2, sig2);
  k_scale<<<dim3(1), dim3(256), 0, stream>>>(t0, t1, t2, sig2, scales);
  k_prep<<<dim3((C3 * DIMC + 255) / 256), dim3(256), 0, stream>>>(qkv_w, dw_w, proj_w, scales, wq, wp, wd);
  k_transpose<<<dim3(HW / 32, DIMC / 32, BATCH), dim3(256), 0, stream>>>(x, xT);
  gemm_bt<true><<<dim3(HW / 128, C3 / 128, BATCH), dim3(256), 0, stream>>>(
      wq, xT, qkv, C3, HW, DIMC, (long)HW * DIMC, (long)C3 * HW);
  k_dwconv<<<dim3(4, C3, BATCH), dim3(256), 0, stream>>>(qkv, wd, dwo, sumsq);
  k_qk<<<dim3(8, 9, 32), dim3(64), 0, stream>>>(dwo, S);
  k_softmax<<<dim3(32), dim3(64), 0, stream>>>(S, sumsq, temp, P);
  k_pv<<<dim3(64, 3, 32), dim3(256), 0, stream>>>(P, dwo, OT);
  gemm_bt<false><<<dim3(HW / 128, DIMC / 128, BATCH), dim3(256), 0, stream>>>(
      wp, OT, out, DIMC, HW, DIMC, (long)HW * DIMC, (long)DIMC * HW);
}

// Round 3
// 613.899 us; speedup vs baseline: 2.8634x; 1.5058x over previous
//
#include <hip/hip_runtime.h>
#include <stdint.h>

typedef __bf16 bf16x8 __attribute__((ext_vector_type(8)));
typedef float f32x4 __attribute__((ext_vector_type(4)));
typedef unsigned short us4 __attribute__((ext_vector_type(4)));
typedef unsigned short us8 __attribute__((ext_vector_type(8)));

#define DIMC 384
#define HEADS 8
#define BATCH 4
#define HW 16384
#define C3 1152
#define CHD 48

__device__ __forceinline__ unsigned short f2b(float f) {
  unsigned int u = __float_as_uint(f);
  u = (u + 0x7fffu + ((u >> 16) & 1u)) >> 16;
  return (unsigned short)u;
}
__device__ __forceinline__ float b2f(unsigned short h) {
  return __uint_as_float(((unsigned int)h) << 16);
}

// ---------------- power iteration stage 1: t = W^T u (qkv, proj) -------------
__global__ __launch_bounds__(384) void k_wtu(
    const float* __restrict__ qkv_w, const float* __restrict__ proj_w,
    const float* __restrict__ u_qkv, const float* __restrict__ u_proj,
    float* __restrict__ t0, float* __restrict__ t2) {
  int mat = blockIdx.y;
  const float* W = mat ? proj_w : qkv_w;
  const float* u = mat ? u_proj : u_qkv;
  float* t = mat ? t2 : t0;
  int H = mat ? DIMC : C3;
  int r0 = blockIdx.x * 128;
  if (r0 >= H) return;
  int c = threadIdx.x;  // < 384, coalesced over columns
  float acc = 0.f;
  int rend = min(r0 + 128, H);
  for (int r = r0; r < rend; ++r) acc += W[(long)r * DIMC + c] * u[r];
  atomicAdd(&t[c], acc);
}

// ---------------- stage 1 for depthwise weight (1152x9) ----------------------
__global__ __launch_bounds__(256) void k_wtu_dw(
    const float* __restrict__ dw_w, const float* __restrict__ u_dw,
    float* __restrict__ t1) {
  float acc[9] = {};
  for (int r = threadIdx.x; r < C3; r += 256) {
    float ur = u_dw[r];
#pragma unroll
    for (int j = 0; j < 9; ++j) acc[j] += dw_w[r * 9 + j] * ur;
  }
  __shared__ float sh[9];
  if (threadIdx.x < 9) sh[threadIdx.x] = 0.f;
  __syncthreads();
#pragma unroll
  for (int j = 0; j < 9; ++j) atomicAdd(&sh[j], acc[j]);
  __syncthreads();
  if (threadIdx.x < 9) t1[threadIdx.x] = sh[threadIdx.x];
}

// ---------------- stage 2: sig2[mat] = |W t|^2, one wave per row -------------
__global__ __launch_bounds__(256) void k_wv(
    const float* __restrict__ qkv_w, const float* __restrict__ dw_w,
    const float* __restrict__ proj_w, const float* __restrict__ t0,
    const float* __restrict__ t1, const float* __restrict__ t2,
    float* __restrict__ sig2) {
  int mat = blockIdx.y;
  const float* W; const float* t; int H, Kc;
  if (mat == 0) { W = qkv_w; t = t0; H = C3; Kc = DIMC; }
  else if (mat == 1) { W = dw_w; t = t1; H = C3; Kc = 9; }
  else { W = proj_w; t = t2; H = DIMC; Kc = DIMC; }
  int wave = threadIdx.x >> 6, lane = threadIdx.x & 63;
  int r = blockIdx.x * 4 + wave;
  if (r >= H) return;
  float acc = 0.f;
  for (int c = lane; c < Kc; c += 64) acc += W[(long)r * Kc + c] * t[c];
  for (int off = 32; off; off >>= 1) acc += __shfl_down(acc, off);
  if (lane == 0) atomicAdd(&sig2[mat], acc * acc);
}

// ---------------- stage 3: scales[mat] = 1/(sqrt(sig2)/max(|t|,eps) + eps) ---
__global__ __launch_bounds__(256) void k_scale(
    const float* __restrict__ t0, const float* __restrict__ t1,
    const float* __restrict__ t2, const float* __restrict__ sig2,
    float* __restrict__ scales) {
  __shared__ float red[256];
  int tid = threadIdx.x;
  const float* ts[3] = {t0, t1, t2};
  const int ks[3] = {DIMC, 9, DIMC};
  for (int m = 0; m < 3; ++m) {
    float ss = 0.f;
    for (int c = tid; c < ks[m]; c += 256) ss += ts[m][c] * ts[m][c];
    red[tid] = ss; __syncthreads();
    for (int s = 128; s; s >>= 1) { if (tid < s) red[tid] += red[tid + s]; __syncthreads(); }
    if (tid == 0) {
      float tn = fmaxf(sqrtf(red[0]), 1e-12f);
      float sigma = sqrtf(sig2[m]) / tn;
      scales[m] = 1.0f / (sigma + 1e-12f);
    }
    __syncthreads();
  }
}

// ---------------- scale + convert weights -----------------------------------
__global__ __launch_bounds__(256) void k_prep(
    const float* __restrict__ qkv_w, const float* __restrict__ dw_w,
    const float* __restrict__ proj_w, const float* __restrict__ scales,
    unsigned short* __restrict__ wq, unsigned short* __restrict__ wp,
    float* __restrict__ wd) {
  int i = blockIdx.x * 256 + threadIdx.x;
  float sq = scales[0], sd = scales[1], sp = scales[2];
  if (i < C3 * DIMC) wq[i] = f2b(qkv_w[i] * sq);
  if (i < DIMC * DIMC) wp[i] = f2b(proj_w[i] * sp);
  if (i < C3 * 9) wd[i] = dw_w[i] * sd;
}

// ---------------- x (B,C,HW) fp32 -> xT (B,HW,C) bf16 ------------------------
__global__ __launch_bounds__(256) void k_transpose(
    const float* __restrict__ x, unsigned short* __restrict__ xT) {
  __shared__ float tile[32][33];
  int b = blockIdx.z;
  int c0 = blockIdx.y * 32, n0 = blockIdx.x * 32;
  int tx = threadIdx.x & 31, ty = threadIdx.x >> 5;
  const float* xb = x + (long)b * DIMC * HW;
  for (int i = ty; i < 32; i += 8)
    tile[i][tx] = xb[(long)(c0 + i) * HW + n0 + tx];
  __syncthreads();
  unsigned short* xTb = xT + (long)b * HW * DIMC;
  for (int i = ty; i < 32; i += 8)
    xTb[(long)(n0 + i) * DIMC + c0 + tx] = f2b(tile[tx][i]);
}

// ---------------- bf16 MFMA GEMM, C = A(MxK) * BT(NxK)^T ---------------------
template <bool BF16_OUT>
__global__ __launch_bounds__(256) void gemm_bt(
    const unsigned short* __restrict__ A, const unsigned short* __restrict__ BT,
    void* __restrict__ Cv, int M, int N, int K, long sB, long sC) {
  __shared__ __align__(16) unsigned short As[128][32];
  __shared__ __align__(16) unsigned short Bs[128][32];
  const unsigned short* Ab = A;  // weights shared across batch
  const unsigned short* Bb = BT + (long)blockIdx.z * sB;
  int tid = threadIdx.x;
  int m0 = blockIdx.y * 128, n0 = blockIdx.x * 128;
  int wave = tid >> 6, lane = tid & 63;
  int wm = (wave >> 1) * 64, wn = (wave & 1) * 64;
  int qm = lane & 15, qko = (lane >> 4) * 8;
  int r0 = tid >> 2, ko0 = (tid & 3) * 8;
  f32x4 acc[4][4] = {};
  for (int k0 = 0; k0 < K; k0 += 32) {
    __syncthreads();
    *(int4*)(&As[r0][ko0]) = *(const int4*)(Ab + (long)(m0 + r0) * K + k0 + ko0);
    *(int4*)(&As[r0 + 64][ko0]) = *(const int4*)(Ab + (long)(m0 + r0 + 64) * K + k0 + ko0);
    *(int4*)(&Bs[r0][ko0]) = *(const int4*)(Bb + (long)(n0 + r0) * K + k0 + ko0);
    *(int4*)(&Bs[r0 + 64][ko0]) = *(const int4*)(Bb + (long)(n0 + r0 + 64) * K + k0 + ko0);
    __syncthreads();
    bf16x8 av[4], bv[4];
#pragma unroll
    for (int i = 0; i < 4; ++i) av[i] = *(const bf16x8*)(&As[wm + i * 16 + qm][qko]);
#pragma unroll
    for (int i = 0; i < 4; ++i) bv[i] = *(const bf16x8*)(&Bs[wn + i * 16 + qm][qko]);
#pragma unroll
    for (int mi = 0; mi < 4; ++mi)
#pragma unroll
      for (int ni = 0; ni < 4; ++ni)
        acc[mi][ni] = __builtin_amdgcn_mfma_f32_16x16x32_bf16(av[mi], bv[ni], acc[mi][ni], 0, 0, 0);
  }
  int col = lane & 15, rowq = (lane >> 4) * 4;
  if (BF16_OUT) {
    unsigned short* Cb = (unsigned short*)Cv + (long)blockIdx.z * sC;
    for (int mi = 0; mi < 4; ++mi)
      for (int ni = 0; ni < 4; ++ni)
        for (int r = 0; r < 4; ++r) {
          int m = m0 + wm + mi * 16 + rowq + r;
          int n = n0 + wn + ni * 16 + col;
          Cb[(long)m * N + n] = f2b(acc[mi][ni][r]);
        }
  } else {
    float* Cb = (float*)Cv + (long)blockIdx.z * sC;
    for (int mi = 0; mi < 4; ++mi)
      for (int ni = 0; ni < 4; ++ni)
        for (int r = 0; r < 4; ++r) {
          int m = m0 + wm + mi * 16 + rowq + r;
          int n = n0 + wn + ni * 16 + col;
          Cb[(long)m * N + n] = acc[mi][ni][r];
        }
  }
}

// ---------------- depthwise 3x3 (SAME) + sumsq, vectorized -------------------
// Each thread: one 8-px strip; halos via wave shuffles (16 segs/row in-wave).
__global__ __launch_bounds__(256) void k_dwconv(
    const unsigned short* __restrict__ qkv, const float* __restrict__ wd,
    unsigned short* __restrict__ out, float* __restrict__ sumsq) {
  int b = blockIdx.z, c = blockIdx.y, y0 = blockIdx.x * 16;
  const unsigned short* in = qkv + ((long)b * C3 + c) * HW;
  unsigned short* o = out + ((long)b * C3 + c) * HW;
  float w[9];
#pragma unroll
  for (int i = 0; i < 9; ++i) w[i] = wd[c * 9 + i];
  int tid = threadIdx.x;
  int r = tid >> 4, s = tid & 15;
  int y = y0 + r, x0 = s * 8;
  float acc[8] = {};
#pragma unroll
  for (int dy = 0; dy < 3; ++dy) {
    int yy = y + dy - 1;
    float a[10];
    if (yy >= 0 && yy < 128) {
      uint4 pk = *(const uint4*)(in + yy * 128 + x0);
      a[1] = __uint_as_float(pk.x << 16);
      a[2] = __uint_as_float(pk.x & 0xffff0000u);
      a[3] = __uint_as_float(pk.y << 16);
      a[4] = __uint_as_float(pk.y & 0xffff0000u);
      a[5] = __uint_as_float(pk.z << 16);
      a[6] = __uint_as_float(pk.z & 0xffff0000u);
      a[7] = __uint_as_float(pk.w << 16);
      a[8] = __uint_as_float(pk.w & 0xffff0000u);
    } else {
#pragma unroll
      for (int j = 1; j <= 8; ++j) a[j] = 0.f;
    }
    float lv = __shfl_up(a[8], 1);
    float rv = __shfl_down(a[1], 1);
    a[0] = (s == 0) ? 0.f : lv;
    a[9] = (s == 15) ? 0.f : rv;
    float w0 = w[dy * 3], w1 = w[dy * 3 + 1], w2 = w[dy * 3 + 2];
#pragma unroll
    for (int j = 0; j < 8; ++j)
      acc[j] += w0 * a[j] + w1 * a[j + 1] + w2 * a[j + 2];
  }
  float ss = 0.f;
  us8 st;
#pragma unroll
  for (int j = 0; j < 8; ++j) {
    unsigned short ob = f2b(acc[j]);
    st[j] = ob;
    float av = b2f(ob);
    ss += av * av;
  }
  *(us8*)(o + y * 128 + x0) = st;
  __shared__ float red[256];
  red[tid] = ss; __syncthreads();
  for (int t = 128; t > 0; t >>= 1) { if (tid < t) red[tid] += red[tid + t]; __syncthreads(); }
  if (tid == 0 && c < 2 * DIMC) atomicAdd(&sumsq[b * 2 * DIMC + c], red[0]);
}

// ---------------- S = Q K^T (unnormalized), fp32 atomic partials -------------
__global__ __launch_bounds__(64) void k_qk(
    const unsigned short* __restrict__ dwo, float* __restrict__ S) {
  int bh = blockIdx.z, b = bh >> 3, h = bh & 7;
  int tile = blockIdx.y;
  int tm = (tile / 3) * 16, tn = (tile % 3) * 16;
  int k0 = blockIdx.x * 2048;
  const unsigned short* Q = dwo + ((long)b * C3 + h * CHD) * HW;
  const unsigned short* Km = dwo + ((long)b * C3 + DIMC + h * CHD) * HW;
  int lane = threadIdx.x;
  int fm = lane & 15, fk = (lane >> 4) * 8;
  const unsigned short* qrow = Q + (long)(tm + fm) * HW;
  const unsigned short* krow = Km + (long)(tn + fm) * HW;
  f32x4 acc = {};
  for (int k = k0; k < k0 + 2048; k += 32) {
    bf16x8 a = *(const bf16x8*)(qrow + k + fk);
    bf16x8 bv = *(const bf16x8*)(krow + k + fk);
    acc = __builtin_amdgcn_mfma_f32_16x16x32_bf16(a, bv, acc, 0, 0, 0);
  }
  int col = lane & 15, rowq = (lane >> 4) * 4;
  float* Sb = S + (long)bh * CHD * CHD;
#pragma unroll
  for (int r = 0; r < 4; ++r)
    atomicAdd(&Sb[(tm + rowq + r) * CHD + tn + col], acc[r]);
}

// ---------------- normalize + temperature + clamp + softmax -> P bf16 (48x64) -
__global__ __launch_bounds__(64) void k_softmax(
    const float* __restrict__ S, const float* __restrict__ sumsq,
    const float* __restrict__ temperature, unsigned short* __restrict__ P) {
  int bh = blockIdx.x, b = bh >> 3, h = bh & 7;
  float t = temperature[h];
  const float* Sb = S + (long)bh * CHD * CHD;
  const float* nq = sumsq + b * 2 * DIMC + h * CHD;
  const float* nk = sumsq + b * 2 * DIMC + DIMC + h * CHD;
  unsigned short* Pb = P + (long)bh * CHD * 64;
  int i = threadIdx.x;
  if (i < CHD) {
    float qn = fmaxf(sqrtf(nq[i]), 1e-12f);
    float row[CHD];
    float mx = -1e30f;
#pragma unroll
    for (int j = 0; j < CHD; ++j) {
      float kn = fmaxf(sqrtf(nk[j]), 1e-12f);
      float v = Sb[i * CHD + j] / (qn * kn) * t;
      v = fminf(fmaxf(v, -50.f), 50.f);
      row[j] = v;
      mx = fmaxf(mx, v);
    }
    float sum = 0.f;
#pragma unroll
    for (int j = 0; j < CHD; ++j) { float e = __expf(row[j] - mx); row[j] = e; sum += e; }
    float inv = 1.0f / sum;
#pragma unroll
    for (int j = 0; j < 64; ++j)
      Pb[i * 64 + j] = f2b(j < CHD ? row[j] * inv : 0.0f);
  }
}

// ---------------- O^T = (P @ V)^T, bf16, (B, HW, 384) ------------------------
__global__ __launch_bounds__(256) void k_pv(
    const unsigned short* __restrict__ P, const unsigned short* __restrict__ dwo,
    unsigned short* __restrict__ OT) {
  int bh = blockIdx.z, b = bh >> 3, h = bh & 7;
  int tm = blockIdx.y * 16;
  int wave = threadIdx.x >> 6, lane = threadIdx.x & 63;
  int fm = lane & 15, fq = lane >> 4;
  const unsigned short* Pb = P + (long)bh * CHD * 64;
  const unsigned short* V = dwo + ((long)b * C3 + 2 * DIMC + h * CHD) * HW;
  bf16x8 a0 = *(const bf16x8*)(Pb + (tm + fm) * 64 + fq * 8);
  bf16x8 a1 = *(const bf16x8*)(Pb + (tm + fm) * 64 + 32 + fq * 8);
  unsigned short* OTb = OT + (long)b * HW * DIMC;
  for (int nt = 0; nt < 4; ++nt) {
    int n0 = (blockIdx.x * 16 + wave * 4 + nt) * 16;
    bf16x8 b0, b1;
#pragma unroll
    for (int j = 0; j < 8; ++j) {
      int kk0 = fq * 8 + j;
      ((__bf16*)&b0)[j] = *(const __bf16*)(V + (long)kk0 * HW + n0 + fm);
      int kk1 = 32 + fq * 8 + j;
      ((__bf16*)&b1)[j] = (kk1 < CHD) ? *(const __bf16*)(V + (long)kk1 * HW + n0 + fm)
                                      : (__bf16)0.0f;
    }
    f32x4 acc = {};
    acc = __builtin_amdgcn_mfma_f32_16x16x32_bf16(a0, b0, acc, 0, 0, 0);
    acc = __builtin_amdgcn_mfma_f32_16x16x32_bf16(a1, b1, acc, 0, 0, 0);
    int n = n0 + (lane & 15);
    int cg = h * CHD + tm + fq * 4;
    us4 st;
#pragma unroll
    for (int r = 0; r < 4; ++r) st[r] = f2b(acc[r]);
    *(us4*)(OTb + (long)n * DIMC + cg) = st;
  }
}

extern "C" void kernel_launch(void* const* d_in, const int* in_sizes, int n_in,
                              void* d_out, int out_size, void* d_ws, size_t ws_size,
                              hipStream_t stream) {
  const float* x = (const float*)d_in[0];
  const float* qkv_w = (const float*)d_in[1];
  const float* dw_w = (const float*)d_in[2];
  const float* proj_w = (const float*)d_in[3];
  const float* temp = (const float*)d_in[4];
  const float* u_qkv = (const float*)d_in[5];
  const float* u_dw = (const float*)d_in[6];
  const float* u_proj = (const float*)d_in[7];
  float* out = (float*)d_out;

  char* ws = (char*)d_ws;
  size_t cur = 0;
  auto take = [&](size_t n) { size_t r = cur; cur += (n + 255) & ~(size_t)255; return r; };
  // power-iteration scratch: t0 | t1 | t2 | sig2 contiguous -> one memset
  float* t0 = (float*)(ws + take(DIMC * 4));        // 384
  float* t1 = (float*)(ws + take(16 * 4));          // 9 (padded)
  float* t2 = (float*)(ws + take(DIMC * 4));        // 384
  float* sig2 = (float*)(ws + take(4 * 4));         // 3
  size_t tbytes = cur;                              // all of the above
  float* scales = (float*)(ws + take(3 * 4));
  float* sumsq = (float*)(ws + take((size_t)BATCH * 2 * DIMC * 4));
  float* S = (float*)(ws + take((size_t)32 * CHD * CHD * 4));
  unsigned short* P = (unsigned short*)(ws + take((size_t)32 * CHD * 64 * 2));
  unsigned short* wq = (unsigned short*)(ws + take((size_t)C3 * DIMC * 2));
  unsigned short* wp = (unsigned short*)(ws + take((size_t)DIMC * DIMC * 2));
  float* wd = (float*)(ws + take((size_t)C3 * 9 * 4));
  unsigned short* xT = (unsigned short*)(ws + take((size_t)BATCH * HW * DIMC * 2));
  unsigned short* qkv = (unsigned short*)(ws + take((size_t)BATCH * C3 * HW * 2));
  unsigned short* dwo = (unsigned short*)(ws + take((size_t)BATCH * C3 * HW * 2));
  unsigned short* OT = xT;  // xT is dead after gemm1; reuse for O^T

  hipMemsetAsync(ws, 0, tbytes, stream);  // t0,t1,t2,sig2
  hipMemsetAsync(sumsq, 0, (size_t)BATCH * 2 * DIMC * 4, stream);
  hipMemsetAsync(S, 0, (size_t)32 * CHD * CHD * 4, stream);

  k_wtu<<<dim3(9, 2), dim3(384), 0, stream>>>(qkv_w, proj_w, u_qkv, u_proj, t0, t2);
  k_wtu_dw<<<dim3(1), dim3(256), 0, stream>>>(dw_w, u_dw, t1);
  k_wv<<<dim3(288, 3), dim3(256), 0, stream>>>(qkv_w, dw_w, proj_w, t0, t1, t2, sig2);
  k_scale<<<dim3(1), dim3(256), 0, stream>>>(t0, t1, t2, sig2, scales);
  k_prep<<<dim3((C3 * DIMC + 255) / 256), dim3(256), 0, stream>>>(qkv_w, dw_w, proj_w, scales, wq, wp, wd);
  k_transpose<<<dim3(HW / 32, DIMC / 32, BATCH), dim3(256), 0, stream>>>(x, xT);
  gemm_bt<true><<<dim3(HW / 128, C3 / 128, BATCH), dim3(256), 0, stream>>>(
      wq, xT, qkv, C3, HW, DIMC, (long)HW * DIMC, (long)C3 * HW);
  k_dwconv<<<dim3(8, C3, BATCH), dim3(256), 0, stream>>>(qkv, wd, dwo, sumsq);
  k_qk<<<dim3(8, 9, 32), dim3(64), 0, stream>>>(dwo, S);
  k_softmax<<<dim3(32), dim3(64), 0, stream>>>(S, sumsq, temp, P);
  k_pv<<<dim3(64, 3, 32), dim3(256), 0, stream>>>(P, dwo, OT);
  gemm_bt<false><<<dim3(HW / 128, DIMC / 128, BATCH), dim3(256), 0, stream>>>(
      wp, OT, out, DIMC, HW, DIMC, (long)HW * DIMC, (long)DIMC * HW);
}